// Round 1
// baseline (151.351 us; speedup 1.0000x reference)
//
#include <hip/hip_runtime.h>
#include <hip/hip_bf16.h>
#include <math.h>

// Problem constants (from reference): logits (2048, 3, 32000) f32, targets (2048, 4) int
#define VOCAB   32000
#define BATCH   2048
#define SEQ     3
#define ROWS    (BATCH * SEQ)        // 6144 softmax rows
#define THREADS 320                  // 5 waves; 32000/4 = 8000 float4 = 320 * 25
#define ITERS   25
#define NBINS   15

// Combine two online-softmax partials (max m, scaled sum s, argmax idx).
// Tie-break: smaller global index (first occurrence), matching jnp.argmax.
__device__ __forceinline__ void combine(float& m, float& s, int& idx,
                                        float m2, float s2, int idx2) {
    if (m2 > m)      { s = s * __expf(m - m2) + s2; m = m2; idx = idx2; }
    else if (m2 < m) { s = s + s2 * __expf(m2 - m); }
    else             { s += s2; idx = (idx2 < idx) ? idx2 : idx; }
}

// One block per row: online max / sum-of-exp / argmax in a single HBM pass.
__global__ __launch_bounds__(THREADS) void row_softmax_stats(
        const float* __restrict__ logits,
        float* __restrict__ maxprob,   // [ROWS] = 1/sumexp = max softmax prob
        int*   __restrict__ amax)      // [ROWS] = argmax index
{
    const int row = blockIdx.x;
    const int t   = threadIdx.x;
    const float4* base = (const float4*)(logits + (size_t)row * VOCAB);

    float m = -INFINITY;
    float s = 0.0f;
    int   idx = 0;

    for (int i = 0; i < ITERS; ++i) {
        const int f4 = t + THREADS * i;          // coalesced: lane-consecutive float4
        float4 v = base[f4];
        float lm = fmaxf(fmaxf(v.x, v.y), fmaxf(v.z, v.w));
        if (lm > m) {                             // strict >: keeps first occurrence
            s *= __expf(m - lm);                  // m==-inf -> exp(-inf)=0, s stays 0
            m = lm;
            int j = (v.x == lm) ? 0 : (v.y == lm) ? 1 : (v.z == lm) ? 2 : 3;
            idx = f4 * 4 + j;
        }
        s += __expf(v.x - m);
        s += __expf(v.y - m);
        s += __expf(v.z - m);
        s += __expf(v.w - m);
    }

    // wave (64-lane) shuffle reduce
    for (int off = 32; off > 0; off >>= 1) {
        float m2 = __shfl_down(m, off);
        float s2 = __shfl_down(s, off);
        int   i2 = __shfl_down(idx, off);
        combine(m, s, idx, m2, s2, i2);
    }

    // 5 waves -> LDS -> thread 0
    __shared__ float sm[THREADS / 64], ss[THREADS / 64];
    __shared__ int   si[THREADS / 64];
    const int wave = t >> 6;
    if ((t & 63) == 0) { sm[wave] = m; ss[wave] = s; si[wave] = idx; }
    __syncthreads();
    if (t == 0) {
        for (int w = 1; w < THREADS / 64; ++w) combine(m, s, idx, sm[w], ss[w], si[w]);
        maxprob[row] = 1.0f / s;   // exp(xmax-xmax)=1 exactly -> max prob = 1/s
        amax[row]    = idx;
    }
}

// Single block: confidences, accuracies, 15-bin ECE. O(B) work, ~µs.
__global__ __launch_bounds__(256) void ece_reduce(
        const float* __restrict__ maxprob,
        const int*   __restrict__ amax,
        const int*   __restrict__ targets,   // [B][4] int32
        float*       __restrict__ out)
{
    const int t = threadIdx.x;

    float c_cnt[NBINS], c_conf[NBINS], c_acc[NBINS];
    #pragma unroll
    for (int i = 0; i < NBINS; ++i) { c_cnt[i] = 0.f; c_conf[i] = 0.f; c_acc[i] = 0.f; }

    for (int b = t; b < BATCH; b += 256) {
        float p0 = maxprob[b * 3 + 0];
        float p1 = maxprob[b * 3 + 1];
        float p2 = maxprob[b * 3 + 2];
        float conf = (p0 * p1) * p2;             // jnp.prod order

        float acc = 0.f;
        acc += (amax[b * 3 + 0] == targets[b * 4 + 1]) ? 1.f : 0.f;
        acc += (amax[b * 3 + 1] == targets[b * 4 + 2]) ? 1.f : 0.f;
        acc += (amax[b * 3 + 2] == targets[b * 4 + 3]) ? 1.f : 0.f;
        float row_acc = acc / 3.0f;              // jnp.mean over 3

        // static-index bin accumulate (runtime-indexed arrays would spill to scratch)
        #pragma unroll
        for (int i = 0; i < NBINS; ++i) {
            float lo = (float)i       * (1.0f / 15.0f);
            float up = (float)(i + 1) * (1.0f / 15.0f);
            bool in = (conf > lo) && (conf <= up);
            if (in) { c_cnt[i] += 1.f; c_conf[i] += conf; c_acc[i] += row_acc; }
        }
    }

    // wave reduce each accumulator
    #pragma unroll
    for (int i = 0; i < NBINS; ++i) {
        for (int off = 32; off > 0; off >>= 1) {
            c_cnt[i]  += __shfl_down(c_cnt[i],  off);
            c_conf[i] += __shfl_down(c_conf[i], off);
            c_acc[i]  += __shfl_down(c_acc[i],  off);
        }
    }

    __shared__ float s_cnt[NBINS], s_conf[NBINS], s_acc[NBINS];
    if (t < NBINS) { s_cnt[t] = 0.f; s_conf[t] = 0.f; s_acc[t] = 0.f; }
    __syncthreads();
    if ((t & 63) == 0) {
        #pragma unroll
        for (int i = 0; i < NBINS; ++i) {
            atomicAdd(&s_cnt[i],  c_cnt[i]);
            atomicAdd(&s_conf[i], c_conf[i]);
            atomicAdd(&s_acc[i],  c_acc[i]);
        }
    }
    __syncthreads();
    if (t == 0) {
        float ece = 0.f;
        #pragma unroll
        for (int i = 0; i < NBINS; ++i) {
            float cnt = s_cnt[i];
            if (cnt > 0.f) {
                float prop     = cnt / (float)BATCH;
                float safe_cnt = fmaxf(cnt, 1.0f);
                float avg_conf = s_conf[i] / safe_cnt;
                float avg_acc  = s_acc[i]  / safe_cnt;
                ece += fabsf(avg_conf - avg_acc) * prop;
            }
        }
        out[0] = ece;
    }
}

extern "C" void kernel_launch(void* const* d_in, const int* in_sizes, int n_in,
                              void* d_out, int out_size, void* d_ws, size_t ws_size,
                              hipStream_t stream) {
    const float* logits  = (const float*)d_in[0];
    const int*   targets = (const int*)d_in[1];   // harness: integer -> const int*
    float*       out     = (float*)d_out;

    float* maxprob = (float*)d_ws;                       // 6144 floats
    int*   amax    = (int*)((char*)d_ws + ROWS * sizeof(float)); // 6144 ints

    row_softmax_stats<<<ROWS, THREADS, 0, stream>>>(logits, maxprob, amax);
    ece_reduce<<<1, 256, 0, stream>>>(maxprob, amax, targets, out);
}